// Round 3
// baseline (456.311 us; speedup 1.0000x reference)
//
#include <hip/hip_runtime.h>

// EEBasis: out[n, s] = exp(-|zeta[s]| * sqrt(diffs[n, cidx[s], 3]))
// N = 262144 rows, 64 centers x float4, 256 shells (4 per center).
// Streaming 256 MiB read + 256 MiB write -> ~85 us HBM floor.
//
// Measured structure (rounds 0-2): harness re-poison fills (2 x 1 GiB at
// ~165 us, HBM roofline) dominate the 433-444 us metric; this kernel is
// the ~104-114 us residual. Round-2 post-mortem: nontemporal hints cost
// ~10 us -> reverted. Kept: 4x unroll (4 independent global_load_dwordx4
// in flight per wave) and the wave-uniform identity fast path
// (cidx = repeat(arange(64),4) -> c[k]==lane; skips the serialized
// ds_bpermute + lgkmcnt(0) chain; bit-identical since __shfl(r,lane)==r).
// General shfl fallback retained for arbitrary cidx.

__global__ __launch_bounds__(256) void ee_basis_kernel(
    const float4* __restrict__ diffs,   // [N*64] float4
    const float*  __restrict__ zetas,   // [256]
    const int*    __restrict__ cidx,    // [256]
    float4*       __restrict__ out,     // [N*64] float4 (= [N,256] floats)
    int nrows)
{
    const int tid   = blockIdx.x * blockDim.x + threadIdx.x;
    const int lane  = threadIdx.x & 63;          // = center this lane loads
    const int wave  = tid >> 6;                  // global wave id
    const int waves = (gridDim.x * blockDim.x) >> 6;

    // Loop-invariant per-lane constants for shells 4*lane .. 4*lane+3.
    // zetas/cidx are 1 KiB each -> L1-resident after first touch.
    const int s0 = lane << 2;
    float nb[4]; int c[4];
    #pragma unroll
    for (int k = 0; k < 4; ++k) {
        nb[k] = -fabsf(zetas[s0 + k]) * 1.4426950408889634f;  // -|z|*log2(e)
        c[k]  = cidx[s0 + k];                                  // in [0, 64)
    }

    // Wave-uniform fast-path check (true for repeat(arange(64),4)).
    const bool ident = __all((c[0] == lane) & (c[1] == lane) &
                             (c[2] == lane) & (c[3] == lane));

    const size_t lstride = (size_t)waves * 64;   // elements between my rows

    if (ident) {
        int n = wave;
        // 4x unrolled: 4 independent loads in flight before any use.
        for (; n + 3 * waves < nrows; n += 4 * waves) {
            const size_t i0 = (size_t)n * 64 + lane;
            const size_t i1 = i0 + lstride;
            const size_t i2 = i1 + lstride;
            const size_t i3 = i2 + lstride;

            const float4 d0 = diffs[i0];
            const float4 d1 = diffs[i1];
            const float4 d2 = diffs[i2];
            const float4 d3 = diffs[i3];

            const float r0 = sqrtf(d0.w);
            const float r1 = sqrtf(d1.w);
            const float r2 = sqrtf(d2.w);
            const float r3 = sqrtf(d3.w);

            float4 o0, o1, o2, o3;
            o0.x = exp2f(nb[0] * r0); o0.y = exp2f(nb[1] * r0);
            o0.z = exp2f(nb[2] * r0); o0.w = exp2f(nb[3] * r0);
            o1.x = exp2f(nb[0] * r1); o1.y = exp2f(nb[1] * r1);
            o1.z = exp2f(nb[2] * r1); o1.w = exp2f(nb[3] * r1);
            o2.x = exp2f(nb[0] * r2); o2.y = exp2f(nb[1] * r2);
            o2.z = exp2f(nb[2] * r2); o2.w = exp2f(nb[3] * r2);
            o3.x = exp2f(nb[0] * r3); o3.y = exp2f(nb[1] * r3);
            o3.z = exp2f(nb[2] * r3); o3.w = exp2f(nb[3] * r3);

            out[i0] = o0;
            out[i1] = o1;
            out[i2] = o2;
            out[i3] = o3;
        }
        // Tail (not hit when nrows % (4*waves) == 0; 262144/8192 = 32).
        for (; n < nrows; n += waves) {
            const size_t i = (size_t)n * 64 + lane;
            const float4 d = diffs[i];
            const float  r = sqrtf(d.w);
            float4 o;
            o.x = exp2f(nb[0] * r); o.y = exp2f(nb[1] * r);
            o.z = exp2f(nb[2] * r); o.w = exp2f(nb[3] * r);
            out[i] = o;
        }
    } else {
        // General path: cross-lane gather of r via ds_bpermute.
        for (int n = wave; n < nrows; n += waves) {
            const size_t i = (size_t)n * 64 + lane;
            const float4 d = diffs[i];
            const float  r = sqrtf(d.w);
            float4 o;
            o.x = exp2f(nb[0] * __shfl(r, c[0], 64));
            o.y = exp2f(nb[1] * __shfl(r, c[1], 64));
            o.z = exp2f(nb[2] * __shfl(r, c[2], 64));
            o.w = exp2f(nb[3] * __shfl(r, c[3], 64));
            out[i] = o;
        }
    }
}

extern "C" void kernel_launch(void* const* d_in, const int* in_sizes, int n_in,
                              void* d_out, int out_size, void* d_ws, size_t ws_size,
                              hipStream_t stream) {
    const float4* diffs = (const float4*)d_in[0];
    const float*  zetas = (const float*)d_in[1];
    const int*    cidx  = (const int*)d_in[2];
    float4*       out   = (float4*)d_out;

    const int nrows = in_sizes[0] / 256;   // [N, 64, 4] floats -> N
    const int block = 256;                 // 4 waves/block
    const int grid  = 2048;                // 8192 waves = full occupancy,
                                           // 32 rows/wave (8 unrolled iters)
    ee_basis_kernel<<<grid, block, 0, stream>>>(diffs, zetas, cidx, out, nrows);
}

// Round 4
// 434.268 us; speedup vs baseline: 1.0508x; 1.0508x over previous
//
#include <hip/hip_runtime.h>

// EEBasis: out[n, s] = exp(-|zeta[s]| * sqrt(diffs[n, cidx[s], 3]))
// N = 262144 rows, 64 centers x float4, 256 shells (4 per center).
// Streaming 256 MiB read + 256 MiB write -> ~85 us HBM floor (m13 copy
// ceiling 6.29 TB/s).
//
// Measured structure (rounds 0-3, cross-session repro +-1 us):
//   dur_us = 2 x 1 GiB harness poison fills (~330 us, at HBM roofline,
//   not ours) + this kernel (~104 us residual).
// Round-3 post-mortem: 4x unroll REGRESSED +22 us (VGPR growth past the
// 64-reg occupancy boundary -> 8->4 waves/SIMD; full occupancy with one
// load in flight per wave hides latency better). Reverted to the simple
// one-row-per-wave grid-stride loop.
// This round's single change vs round 0: wave-uniform identity fast path
// (cidx = repeat(arange(64),4) -> c[k]==lane for all lanes), detected via
// __all(); removes 4 serialized ds_bpermute + lgkmcnt(0) per iteration.
// Bit-identical since __shfl(r, lane) == r. General shfl fallback kept.

__global__ __launch_bounds__(256) void ee_basis_kernel(
    const float4* __restrict__ diffs,   // [N*64] float4
    const float*  __restrict__ zetas,   // [256]
    const int*    __restrict__ cidx,    // [256]
    float4*       __restrict__ out,     // [N*64] float4 (= [N,256] floats)
    int nrows)
{
    const int tid   = blockIdx.x * blockDim.x + threadIdx.x;
    const int lane  = threadIdx.x & 63;          // = center this lane loads
    const int wave  = tid >> 6;                  // global wave id = row id
    const int waves = (gridDim.x * blockDim.x) >> 6;

    // Loop-invariant per-lane constants for shells 4*lane .. 4*lane+3.
    // zetas/cidx are 1 KiB each -> L1-resident after first touch.
    const int s0 = lane << 2;
    float nb[4]; int c[4];
    #pragma unroll
    for (int k = 0; k < 4; ++k) {
        nb[k] = -fabsf(zetas[s0 + k]) * 1.4426950408889634f;  // -|z|*log2(e)
        c[k]  = cidx[s0 + k];                                  // in [0, 64)
    }

    // Wave-uniform fast-path check (true for repeat(arange(64),4)).
    const bool ident = __all((c[0] == lane) & (c[1] == lane) &
                             (c[2] == lane) & (c[3] == lane));

    if (ident) {
        // No cross-lane ops: r is lane-local. Same memory pattern as the
        // proven round-0 loop; strictly shorter dependency chain.
        for (int n = wave; n < nrows; n += waves) {
            const size_t i = (size_t)n * 64 + lane;
            const float4 d = diffs[i];
            const float  r = sqrtf(d.w);
            float4 o;
            o.x = exp2f(nb[0] * r);
            o.y = exp2f(nb[1] * r);
            o.z = exp2f(nb[2] * r);
            o.w = exp2f(nb[3] * r);
            out[i] = o;
        }
    } else {
        // General path: cross-lane gather of r via ds_bpermute.
        for (int n = wave; n < nrows; n += waves) {
            const size_t i = (size_t)n * 64 + lane;
            const float4 d = diffs[i];
            const float  r = sqrtf(d.w);
            float4 o;
            o.x = exp2f(nb[0] * __shfl(r, c[0], 64));
            o.y = exp2f(nb[1] * __shfl(r, c[1], 64));
            o.z = exp2f(nb[2] * __shfl(r, c[2], 64));
            o.w = exp2f(nb[3] * __shfl(r, c[3], 64));
            out[i] = o;
        }
    }
}

extern "C" void kernel_launch(void* const* d_in, const int* in_sizes, int n_in,
                              void* d_out, int out_size, void* d_ws, size_t ws_size,
                              hipStream_t stream) {
    const float4* diffs = (const float4*)d_in[0];
    const float*  zetas = (const float*)d_in[1];
    const int*    cidx  = (const int*)d_in[2];
    float4*       out   = (float4*)d_out;

    const int nrows = in_sizes[0] / 256;   // [N, 64, 4] floats -> N
    const int block = 256;                 // 4 waves/block -> 4 rows/iter
    const int grid  = 2048;                // 8192 waves = 1x-resident at
                                           // 8 waves/SIMD, 32 rows each
    ee_basis_kernel<<<grid, block, 0, stream>>>(diffs, zetas, cidx, out, nrows);
}

// Round 5
// 427.145 us; speedup vs baseline: 1.0683x; 1.0167x over previous
//
#include <hip/hip_runtime.h>

// EEBasis: out[n, s] = exp(-|zeta[s]| * sqrt(diffs[n, cidx[s], 3]))
// N = 262144 rows, 64 centers x float4, 256 shells (4 per center).
// Streaming 256 MiB read + 256 MiB write -> ~82-85 us HBM floor.
//
// Measured structure (rounds 0-4, cross-session repro +-1 us):
//   dur_us = 2 x 1 GiB harness poison fills (~330 us, HBM roofline,
//   not ours) + this kernel (~104 us residual).
// Ablation ledger: 4x unroll = +22 us (R3-R4); NT hints = -12 us in the
// unrolled context (R2-R3); ident fast path = ~0 but strictly-shorter
// chain (R4-R0). This round: R4 structure + NT only (single variable).
// Theory: 512 MiB stream > 256 MiB L3; nt = evict-first, avoids L3
// thrash/writeback turnaround. Bytes unchanged.
//
// NOTE: __builtin_nontemporal_* requires native vector types ->
// ext_vector_type(4) float, pointers reinterpreted in kernel_launch.

typedef float float4n __attribute__((ext_vector_type(4)));

__global__ __launch_bounds__(256) void ee_basis_kernel(
    const float4n* __restrict__ diffs,  // [N*64] float4
    const float*   __restrict__ zetas,  // [256]
    const int*     __restrict__ cidx,   // [256]
    float4n*       __restrict__ out,    // [N*64] float4 (= [N,256] floats)
    int nrows)
{
    const int tid   = blockIdx.x * blockDim.x + threadIdx.x;
    const int lane  = threadIdx.x & 63;          // = center this lane loads
    const int wave  = tid >> 6;                  // global wave id = row id
    const int waves = (gridDim.x * blockDim.x) >> 6;

    // Loop-invariant per-lane constants for shells 4*lane .. 4*lane+3.
    // zetas/cidx are 1 KiB each -> L1-resident after first touch.
    const int s0 = lane << 2;
    float nb[4]; int c[4];
    #pragma unroll
    for (int k = 0; k < 4; ++k) {
        nb[k] = -fabsf(zetas[s0 + k]) * 1.4426950408889634f;  // -|z|*log2(e)
        c[k]  = cidx[s0 + k];                                  // in [0, 64)
    }

    // Wave-uniform fast-path check (true for repeat(arange(64),4)).
    // __shfl(r, lane) == r, so the fast path is bit-identical.
    const bool ident = __all((c[0] == lane) & (c[1] == lane) &
                             (c[2] == lane) & (c[3] == lane));

    if (ident) {
        for (int n = wave; n < nrows; n += waves) {
            const size_t i = (size_t)n * 64 + lane;
            const float4n d = __builtin_nontemporal_load(&diffs[i]);
            const float   r = sqrtf(d.w);
            float4n o;
            o.x = exp2f(nb[0] * r);
            o.y = exp2f(nb[1] * r);
            o.z = exp2f(nb[2] * r);
            o.w = exp2f(nb[3] * r);
            __builtin_nontemporal_store(o, &out[i]);
        }
    } else {
        // General path: cross-lane gather of r via ds_bpermute.
        for (int n = wave; n < nrows; n += waves) {
            const size_t i = (size_t)n * 64 + lane;
            const float4n d = __builtin_nontemporal_load(&diffs[i]);
            const float   r = sqrtf(d.w);
            float4n o;
            o.x = exp2f(nb[0] * __shfl(r, c[0], 64));
            o.y = exp2f(nb[1] * __shfl(r, c[1], 64));
            o.z = exp2f(nb[2] * __shfl(r, c[2], 64));
            o.w = exp2f(nb[3] * __shfl(r, c[3], 64));
            __builtin_nontemporal_store(o, &out[i]);
        }
    }
}

extern "C" void kernel_launch(void* const* d_in, const int* in_sizes, int n_in,
                              void* d_out, int out_size, void* d_ws, size_t ws_size,
                              hipStream_t stream) {
    const float4n* diffs = (const float4n*)d_in[0];
    const float*   zetas = (const float*)d_in[1];
    const int*     cidx  = (const int*)d_in[2];
    float4n*       out   = (float4n*)d_out;

    const int nrows = in_sizes[0] / 256;   // [N, 64, 4] floats -> N
    const int block = 256;                 // 4 waves/block
    const int grid  = 2048;                // 8192 waves = 8 waves/SIMD
                                           // fully resident, 32 rows each
    ee_basis_kernel<<<grid, block, 0, stream>>>(diffs, zetas, cidx, out, nrows);
}